// Round 2
// baseline (223.324 us; speedup 1.0000x reference)
//
#include <hip/hip_runtime.h>
#include <math.h>
#include <stdint.h>

#define NTOT   8192
#define HALF_N 4096
#define DIM    512
#define INV_T  14.2857142857142857f   // 1/0.07

using s16x8 = __attribute__((ext_vector_type(8))) short;
using f32x4 = __attribute__((ext_vector_type(4))) float;

// All scratch lives in static device globals — no d_ws dependency (R0 crash
// was a device fault consistent with d_ws overrun). Every array is fully
// rewritten on every call; no cross-call state.
__device__ unsigned short g_fnb[NTOT * DIM];   // normalized bf16 matrix, 8 MB
__device__ float g_pos[NTOT];
__device__ float g_sumexp[NTOT];
__device__ int   g_cnt[NTOT];

__device__ __forceinline__ float bf2f(unsigned short u) {
  union { unsigned int i; float f; } v; v.i = ((unsigned int)u) << 16; return v.f;
}
__device__ __forceinline__ unsigned short f2bf(float x) {
  union { float f; unsigned int i; } v; v.f = x;
  unsigned int u = v.i;
  return (unsigned short)((u + 0x7FFFu + ((u >> 16) & 1u)) >> 16);
}

// ---------------- kernel 1: normalize rows -> bf16; zero the stats ----------------
// one wave per row; lane covers 8 floats (2x float4)
__global__ __launch_bounds__(256) void knorm(const float* __restrict__ f1,
                                             const float* __restrict__ f2) {
  const int gid = blockIdx.x * 256 + threadIdx.x;
  if (gid < NTOT) { g_sumexp[gid] = 0.f; g_cnt[gid] = 0; }

  const int row  = blockIdx.x * 4 + (threadIdx.x >> 6);
  const int lane = threadIdx.x & 63;
  const float* src = (row < HALF_N) ? (f1 + (size_t)row * DIM)
                                    : (f2 + (size_t)(row - HALF_N) * DIM);
  float4 v0 = ((const float4*)src)[lane];
  float4 v1 = ((const float4*)src)[lane + 64];
  float ss = v0.x*v0.x + v0.y*v0.y + v0.z*v0.z + v0.w*v0.w
           + v1.x*v1.x + v1.y*v1.y + v1.z*v1.z + v1.w*v1.w;
  #pragma unroll
  for (int o = 32; o >= 1; o >>= 1) ss += __shfl_xor(ss, o, 64);
  const float sc = 1.0f / fmaxf(sqrtf(ss), 1e-8f);
  ushort4 h0, h1;
  h0.x = f2bf(v0.x * sc); h0.y = f2bf(v0.y * sc);
  h0.z = f2bf(v0.z * sc); h0.w = f2bf(v0.w * sc);
  h1.x = f2bf(v1.x * sc); h1.y = f2bf(v1.y * sc);
  h1.z = f2bf(v1.z * sc); h1.w = f2bf(v1.w * sc);
  ushort4* dst = (ushort4*)(g_fnb + (size_t)row * DIM);
  dst[lane]      = h0;
  dst[lane + 64] = h1;
}

// ---------------- kernel 2: pos[i] = <fn_i, fn_{i^4096}> (bf16 inputs, fp32 acc)
__global__ __launch_bounds__(256) void kpos() {
  const int i    = blockIdx.x * 4 + (threadIdx.x >> 6);
  const int lane = threadIdx.x & 63;
  const ushort4* a = (const ushort4*)(g_fnb + (size_t)i * DIM);
  const ushort4* b = (const ushort4*)(g_fnb + (size_t)(i ^ HALF_N) * DIM);
  float s = 0.f;
  #pragma unroll
  for (int t = 0; t < 2; ++t) {
    ushort4 ua = a[lane + t * 64];
    ushort4 ub = b[lane + t * 64];
    s += bf2f(ua.x)*bf2f(ub.x) + bf2f(ua.y)*bf2f(ub.y)
       + bf2f(ua.z)*bf2f(ub.z) + bf2f(ua.w)*bf2f(ub.w);
  }
  #pragma unroll
  for (int o = 32; o >= 1; o >>= 1) s += __shfl_xor(s, o, 64);
  if (lane == 0) g_pos[i] = s;
}

// ---------------- kernel 3: fused GEMM + row reductions ----------------
// grid: 64 i-blocks x 8 j-chunks. Block: 128 rows x 1024 cols (8 j-tiles of 128).
// 4 waves; wave tile 64x64 (4x4 frags of 16x16x32 bf16 MFMA). BK=32.
__global__ __launch_bounds__(256, 2) void kmain() {
  __shared__ unsigned short As[128 * 32];
  __shared__ unsigned short Bs[128 * 32];

  const int tid  = threadIdx.x;
  const int lane = tid & 63;
  const int w    = tid >> 6;
  const int bi   = blockIdx.x >> 3;
  const int bj   = blockIdx.x & 7;
  const int i0   = bi * 128;
  const int j0c  = bj * 1024;

  const int wr   = (w >> 1) * 64;   // wave row base within 128-tile
  const int wc   = (w & 1) * 64;    // wave col base
  const int lrow = lane & 15;
  const int lq   = lane >> 4;

  // pos values for the 16 rows this lane owns in C fragments
  float posv[4][4];
  #pragma unroll
  for (int mi = 0; mi < 4; ++mi)
    #pragma unroll
    for (int r = 0; r < 4; ++r)
      posv[mi][r] = g_pos[i0 + wr + mi * 16 + lq * 4 + r];

  float se[4][4];
  int   ct[4][4];
  #pragma unroll
  for (int mi = 0; mi < 4; ++mi)
    #pragma unroll
    for (int r = 0; r < 4; ++r) { se[mi][r] = 0.f; ct[mi][r] = 0; }

  // staging map: thread stages rows (tid>>2) and (tid>>2)+64, 8 elems at col (tid&3)*8
  const int srow = tid >> 2;
  const int scol = (tid & 3) * 8;

  for (int jt = 0; jt < 8; ++jt) {
    const int j0 = j0c + jt * 128;
    f32x4 acc[4][4];
    #pragma unroll
    for (int a = 0; a < 4; ++a)
      #pragma unroll
      for (int b = 0; b < 4; ++b) { acc[a][b][0]=0.f; acc[a][b][1]=0.f; acc[a][b][2]=0.f; acc[a][b][3]=0.f; }

    for (int kt = 0; kt < 16; ++kt) {
      __syncthreads();
      const int kbase = kt * 32 + scol;
      *(int4*)(&As[srow * 32 + scol]) =
          *(const int4*)(&g_fnb[(size_t)(i0 + srow) * DIM + kbase]);
      *(int4*)(&As[(srow + 64) * 32 + scol]) =
          *(const int4*)(&g_fnb[(size_t)(i0 + srow + 64) * DIM + kbase]);
      *(int4*)(&Bs[srow * 32 + scol]) =
          *(const int4*)(&g_fnb[(size_t)(j0 + srow) * DIM + kbase]);
      *(int4*)(&Bs[(srow + 64) * 32 + scol]) =
          *(const int4*)(&g_fnb[(size_t)(j0 + srow + 64) * DIM + kbase]);
      __syncthreads();

      s16x8 af[4], bf[4];
      #pragma unroll
      for (int mi = 0; mi < 4; ++mi)
        af[mi] = *(const s16x8*)(&As[(wr + mi * 16 + lrow) * 32 + lq * 8]);
      #pragma unroll
      for (int ni = 0; ni < 4; ++ni)
        bf[ni] = *(const s16x8*)(&Bs[(wc + ni * 16 + lrow) * 32 + lq * 8]);
      #pragma unroll
      for (int mi = 0; mi < 4; ++mi)
        #pragma unroll
        for (int ni = 0; ni < 4; ++ni)
          acc[mi][ni] = __builtin_amdgcn_mfma_f32_16x16x32_bf16(af[mi], bf[ni], acc[mi][ni], 0, 0, 0);
    }

    // epilogue: fold this j-tile into per-row partials
    #pragma unroll
    for (int mi = 0; mi < 4; ++mi) {
      #pragma unroll
      for (int ni = 0; ni < 4; ++ni) {
        const int j = j0 + wc + ni * 16 + lrow;   // C col = lane&15
        #pragma unroll
        for (int r = 0; r < 4; ++r) {
          const int i = i0 + wr + mi * 16 + lq * 4 + r;  // C row = quad*4+reg
          const float c = acc[mi][ni][r];
          float e = __expf(c * INV_T);
          const bool diag = (j == i);
          if (diag) e = 0.f;
          se[mi][r] += e;
          if (!diag && (j != (i ^ HALF_N)) && (c > posv[mi][r])) ct[mi][r]++;
        }
      }
    }
  }

  // reduce across the 16 lanes of each quad-row group, one atomic per row
  #pragma unroll
  for (int mi = 0; mi < 4; ++mi) {
    #pragma unroll
    for (int r = 0; r < 4; ++r) {
      float s = se[mi][r];
      int   c = ct[mi][r];
      #pragma unroll
      for (int o = 1; o < 16; o <<= 1) {
        s += __shfl_xor(s, o, 64);
        c += __shfl_xor(c, o, 64);
      }
      if (lrow == 0) {
        const int i = i0 + wr + mi * 16 + lq * 4 + r;
        atomicAdd(&g_sumexp[i], s);
        atomicAdd(&g_cnt[i], c);
      }
    }
  }
}

// ---------------- kernel 4: finalize the 4 scalars ----------------
__global__ __launch_bounds__(256) void kfin(float* __restrict__ out) {
  const int tid = threadIdx.x;
  float nll = 0.f, t1 = 0.f, t5 = 0.f, mr = 0.f;
  for (int i = tid; i < NTOT; i += 256) {
    nll += -g_pos[i] * INV_T + logf(g_sumexp[i]);
    const int c = g_cnt[i];
    t1 += (c == 0) ? 1.f : 0.f;
    t5 += (c < 5) ? 1.f : 0.f;
    mr += (float)c;
  }
  #pragma unroll
  for (int o = 32; o >= 1; o >>= 1) {
    nll += __shfl_xor(nll, o, 64);
    t1  += __shfl_xor(t1, o, 64);
    t5  += __shfl_xor(t5, o, 64);
    mr  += __shfl_xor(mr, o, 64);
  }
  __shared__ float red[4][4];
  const int wv = tid >> 6, lane = tid & 63;
  if (lane == 0) { red[wv][0] = nll; red[wv][1] = t1; red[wv][2] = t5; red[wv][3] = mr; }
  __syncthreads();
  if (tid == 0) {
    float a = 0.f, b = 0.f, c = 0.f, d = 0.f;
    for (int k = 0; k < 4; ++k) { a += red[k][0]; b += red[k][1]; c += red[k][2]; d += red[k][3]; }
    out[0] = a / (float)NTOT;
    out[1] = b / (float)NTOT;
    out[2] = c / (float)NTOT;
    out[3] = 1.f + d / (float)NTOT;
  }
}

extern "C" void kernel_launch(void* const* d_in, const int* in_sizes, int n_in,
                              void* d_out, int out_size, void* d_ws, size_t ws_size,
                              hipStream_t stream) {
  const float* f1 = (const float*)d_in[0];
  const float* f2 = (const float*)d_in[1];
  float* out = (float*)d_out;

  knorm<<<dim3(2048), dim3(256), 0, stream>>>(f1, f2);
  kpos <<<dim3(2048), dim3(256), 0, stream>>>();
  kmain<<<dim3(512),  dim3(256), 0, stream>>>();
  kfin <<<dim3(1),    dim3(256), 0, stream>>>(out);
}